// Round 3
// baseline (503.573 us; speedup 1.0000x reference)
//
#include <hip/hip_runtime.h>

// Freeverb fully fused: one kernel, 3 phases separated by hand-rolled grid
// barriers (agent-scope atomics + __threadfence per guide §6 G16).
//
// Phase 1: comb bank closed form  y[t] = sum_m fb^(m-1) x[t-mD]  (exact)
// Phase 2: z = h01 (*) y   where h01 = cascade IR of allpass 0,1
// Phase 3: w = h23 (*) z, then stereo mix -> out
//
// Allpass H(z) = -1 + z^-D/(1-fb z^-D)  =>  IR  h = -delta + g,
//   g[m*D] = fb^(m-1)            (NOT (1+fb)*fb^(m-1) — round-2 bug)
// Pair IR:  h01 = delta - g0 - g1 + g0(*)g1   (~276 terms at |c|>3e-7)
// Term lists are built on-device by block 0 (overlapped with phase 1).
//
// Co-residency: 512 blocks x 512 thr, __launch_bounds__(512,4) caps VGPR at
// 128 -> 2 blocks/CU x 256 CU = 512 slots >= 512 blocks -> no deadlock.

#define NTHR 512
#define NBLK 512
#define LISTCAP 512
#define CUT 3e-7f

// ws layout (bytes):
//   0     : unsigned barrier_cells[8]
//   32    : unsigned list_cnt[4]           idx = pair*2 + ch
//   256   : int   lags [4][LISTCAP]
//   8448  : float coefs[4][LISTCAP]
//   16896 : float y[2][T]  then  float z[2][T]

__device__ __forceinline__ void gridbar(unsigned* cells, int b) {
    __syncthreads();
    if (threadIdx.x == 0) {
        __threadfence();   // agent-scope release
        __hip_atomic_fetch_add(&cells[b], 1u, __ATOMIC_RELEASE, __HIP_MEMORY_SCOPE_AGENT);
        while (__hip_atomic_load(&cells[b], __ATOMIC_RELAXED, __HIP_MEMORY_SCOPE_AGENT)
               < gridDim.x) {
            __builtin_amdgcn_s_sleep(8);
        }
    }
    __syncthreads();
    __threadfence();       // agent-scope acquire
}

__global__ __launch_bounds__(NTHR, 4) void freeverb_fused(
    const float* __restrict__ x,
    const float* __restrict__ cfbL, const float* __restrict__ cfbR,
    const float* __restrict__ afbL, const float* __restrict__ afbR,
    const float* __restrict__ wetp, const float* __restrict__ dryp,
    const float* __restrict__ widthp,
    const int* __restrict__ cdL, const int* __restrict__ cdR,
    const int* __restrict__ adL, const int* __restrict__ adR,
    float* __restrict__ out, unsigned char* __restrict__ ws, int T)
{
    unsigned* cells = (unsigned*)ws;
    unsigned* lcnt  = (unsigned*)(ws + 32);
    int*      lags  = (int*)(ws + 256);
    float*    coefs = (float*)(ws + 256 + 4*LISTCAP*4);
    float*    y     = (float*)(ws + 16896);
    float*    z     = y + 2*(size_t)T;
    const int gtid  = blockIdx.x * NTHR + threadIdx.x;
    const int NT    = gridDim.x * NTHR;

    // ---- phase 0 (block 0 only): build 4 allpass-pair term lists ----
    // h = -delta + g with g[m*D] = fb^(m-1); pair list covers the 4 products.
    if (blockIdx.x == 0) {
        const int M = 25;   // singles m<=22, pairs ma+mb<=23 at CUT=3e-7 (fb=.5)
        for (int q = threadIdx.x; q < 4*M*M; q += NTHR) {
            int lidx = q / (M*M);
            int rem  = q - lidx*(M*M);
            int ma = rem / M, mb = rem % M;
            int pair = lidx >> 1, ch = lidx & 1;
            int ia = pair*2, ib = ia+1;
            int   Da = ch ? adR[ia] : adL[ia];
            int   Db = ch ? adR[ib] : adL[ib];
            float fa = ch ? afbR[ia] : afbL[ia];
            float fb = ch ? afbR[ib] : afbL[ib];
            float coef = 1.f; int lag = 0;
            if (ma > 0) { coef *= -powf(fa,(float)(ma-1)); lag += ma*Da; }
            if (mb > 0) { coef *= -powf(fb,(float)(mb-1)); lag += mb*Db; }
            if (fabsf(coef) > CUT) {
                unsigned slot = atomicAdd(&lcnt[lidx], 1u);
                if (slot < LISTCAP) {
                    lags [lidx*LISTCAP+slot] = lag;
                    coefs[lidx*LISTCAP+slot] = coef;
                }
            }
        }
    }

    // ---- phase 1: comb bank -> y  (16 threads/sample, 4-way ILP split) ----
    {
        const int NU = 16*T;
        for (int u = gtid; u < NU; u += NT) {
            int t = u >> 4, f = u & 15, c = f & 7, right = f >> 3;
            int   D  = right ? cdR[c] : cdL[c];
            float fb = right ? cfbR[c] : cfbL[c];
            float c0=1.f, c1=fb, c2=fb*fb, c3=c2*fb, r4=c2*c2;
            float a0=0.f, a1=0.f, a2=0.f, a3=0.f;
            int i0=t-D, i1=i0-D, i2=i1-D, i3=i2-D, s4=4*D;
            while (i3 >= 0) {
                a0=fmaf(c0,x[i0],a0); a1=fmaf(c1,x[i1],a1);
                a2=fmaf(c2,x[i2],a2); a3=fmaf(c3,x[i3],a3);
                c0*=r4; c1*=r4; c2*=r4; c3*=r4;
                i0-=s4; i1-=s4; i2-=s4; i3-=s4;
            }
            if (i0 >= 0) { a0=fmaf(c0,x[i0],a0);
                if (i1 >= 0) { a1=fmaf(c1,x[i1],a1);
                    if (i2 >= 0) a2=fmaf(c2,x[i2],a2); } }
            float acc = (a0+a1)+(a2+a3);
            acc += __shfl_xor(acc, 1);
            acc += __shfl_xor(acc, 2);
            acc += __shfl_xor(acc, 4);
            if (c == 0) y[right*(size_t)T + t] = acc;
        }
    }
    gridbar(cells, 0);

    // ---- phase 2: z = h01 (*) y  (8 threads/sample/channel) ----
    {
        const int NU = 16*T;
        for (int u = gtid; u < NU; u += NT) {
            int t = u >> 4, ch = (u >> 3) & 1, j = u & 7;
            int lidx = ch;                         // pair 0
            const float* in = y + ch*(size_t)T;
            unsigned cnt = lcnt[lidx];
            int count = (cnt < (unsigned)LISTCAP) ? (int)cnt : LISTCAP;
            float acc = 0.f;
            for (int k = j; k < count; k += 8) {
                int idx = t - lags[lidx*LISTCAP+k];
                if (idx >= 0) acc = fmaf(coefs[lidx*LISTCAP+k], in[idx], acc);
            }
            acc += __shfl_xor(acc, 1);
            acc += __shfl_xor(acc, 2);
            acc += __shfl_xor(acc, 4);
            if (j == 0) z[ch*(size_t)T + t] = acc;
        }
    }
    gridbar(cells, 1);

    // ---- phase 3: w = h23 (*) z, mix, store ----
    {
        float wet = wetp[0], dry = dryp[0], width = widthp[0];
        float wet1 = wet*(width+1.f)*0.5f;
        float wet2 = wet*(1.f-width)*0.5f;
        const int NU = 16*T;
        for (int u = gtid; u < NU; u += NT) {
            int t = u >> 4, ch = (u >> 3) & 1, j = u & 7;
            int lidx = 2 + ch;                     // pair 1
            const float* in = z + ch*(size_t)T;
            unsigned cnt = lcnt[lidx];
            int count = (cnt < (unsigned)LISTCAP) ? (int)cnt : LISTCAP;
            float acc = 0.f;
            for (int k = j; k < count; k += 8) {
                int idx = t - lags[lidx*LISTCAP+k];
                if (idx >= 0) acc = fmaf(coefs[lidx*LISTCAP+k], in[idx], acc);
            }
            acc += __shfl_xor(acc, 1);
            acc += __shfl_xor(acc, 2);
            acc += __shfl_xor(acc, 4);
            float other = __shfl_xor(acc, 8);      // the other channel's output
            if (j == 0)
                out[2*(size_t)t + ch] = fmaf(acc, wet1, fmaf(other, wet2, x[t]*dry));
        }
    }
}

extern "C" void kernel_launch(void* const* d_in, const int* in_sizes, int n_in,
                              void* d_out, int out_size, void* d_ws, size_t ws_size,
                              hipStream_t stream) {
    const float* x            = (const float*)d_in[0];
    const float* comb_fb_L    = (const float*)d_in[1];
    const float* comb_fb_R    = (const float*)d_in[2];
    const float* ap_fb_L      = (const float*)d_in[3];
    const float* ap_fb_R      = (const float*)d_in[4];
    const float* wet          = (const float*)d_in[5];
    const float* dry          = (const float*)d_in[6];
    const float* width        = (const float*)d_in[7];
    const int*   comb_delay_L = (const int*)d_in[8];
    const int*   comb_delay_R = (const int*)d_in[9];
    const int*   ap_delay_L   = (const int*)d_in[10];
    const int*   ap_delay_R   = (const int*)d_in[11];
    const int T = in_sizes[0];

    // zero barrier cells + list counters (ws is poisoned 0xAA before every launch)
    hipMemsetAsync(d_ws, 0, 256, stream);

    freeverb_fused<<<NBLK, NTHR, 0, stream>>>(
        x, comb_fb_L, comb_fb_R, ap_fb_L, ap_fb_R,
        wet, dry, width, comb_delay_L, comb_delay_R, ap_delay_L, ap_delay_R,
        (float*)d_out, (unsigned char*)d_ws, T);
}

// Round 4
// 487.467 us; speedup vs baseline: 1.0330x; 1.0330x over previous
//
#include <hip/hip_runtime.h>

// Freeverb fully fused: one kernel, 3 phases separated by hand-rolled grid
// barriers (agent-scope atomics + __threadfence per guide §6 G16).
//
// Phase 1: comb bank closed form  y[t] = sum_m fb^(m-1) x[t-mD]  (exact)
// Phase 2: z = h01 (*) y   where h01 = cascade IR of allpass 0,1
// Phase 3: w = h23 (*) z, then stereo mix -> out
//
// Allpass H(z) = -1 + z^-D/(1-fb z^-D)  =>  IR  h = -delta + g,
//   g[m*D] = fb^(m-1)
// Pair IR:  h01 = delta - g0 - g1 + g0(*)g1   (~276 terms at |c|>3e-7)
//
// ROUND-4 CHANGE (perf only): phases 2/3 remap threads so each thread owns
// one sample and walks the term list serially (u = t*4 + ch*2 + j). All
// lanes sharing (ch,j,k) read contiguous in[t..t+15 - lag_k] -> coalesced
// wave-loads (~4-8 lines) instead of round-3's 64-way scatter (k striped
// across lanes). Round 3: 437 us kernel, VALUBusy 5% = latency-bound.
//
// Co-residency: 512 blocks x 512 thr, __launch_bounds__(512,4) caps VGPR at
// 128 -> 2 blocks/CU x 256 CU = 512 slots >= 512 blocks -> no deadlock.

#define NTHR 512
#define NBLK 512
#define LISTCAP 512
#define CUT 3e-7f

// ws layout (bytes):
//   0     : unsigned barrier_cells[8]
//   32    : unsigned list_cnt[4]           idx = pair*2 + ch
//   256   : int   lags [4][LISTCAP]
//   8448  : float coefs[4][LISTCAP]
//   16896 : float y[2][T]  then  float z[2][T]

__device__ __forceinline__ void gridbar(unsigned* cells, int b) {
    __syncthreads();
    if (threadIdx.x == 0) {
        __threadfence();   // agent-scope release
        __hip_atomic_fetch_add(&cells[b], 1u, __ATOMIC_RELEASE, __HIP_MEMORY_SCOPE_AGENT);
        while (__hip_atomic_load(&cells[b], __ATOMIC_RELAXED, __HIP_MEMORY_SCOPE_AGENT)
               < gridDim.x) {
            __builtin_amdgcn_s_sleep(8);
        }
    }
    __syncthreads();
    __threadfence();       // agent-scope acquire
}

__global__ __launch_bounds__(NTHR, 4) void freeverb_fused(
    const float* __restrict__ x,
    const float* __restrict__ cfbL, const float* __restrict__ cfbR,
    const float* __restrict__ afbL, const float* __restrict__ afbR,
    const float* __restrict__ wetp, const float* __restrict__ dryp,
    const float* __restrict__ widthp,
    const int* __restrict__ cdL, const int* __restrict__ cdR,
    const int* __restrict__ adL, const int* __restrict__ adR,
    float* __restrict__ out, unsigned char* __restrict__ ws, int T)
{
    unsigned* cells = (unsigned*)ws;
    unsigned* lcnt  = (unsigned*)(ws + 32);
    int*      lags  = (int*)(ws + 256);
    float*    coefs = (float*)(ws + 256 + 4*LISTCAP*4);
    float*    y     = (float*)(ws + 16896);
    float*    z     = y + 2*(size_t)T;
    const int gtid  = blockIdx.x * NTHR + threadIdx.x;
    const int NT    = gridDim.x * NTHR;

    // ---- phase 0 (block 0 only): build 4 allpass-pair term lists ----
    // h = -delta + g with g[m*D] = fb^(m-1); pair list covers the 4 products.
    if (blockIdx.x == 0) {
        const int M = 25;   // singles m<=22, pairs ma+mb<=23 at CUT=3e-7 (fb=.5)
        for (int q = threadIdx.x; q < 4*M*M; q += NTHR) {
            int lidx = q / (M*M);
            int rem  = q - lidx*(M*M);
            int ma = rem / M, mb = rem % M;
            int pair = lidx >> 1, ch = lidx & 1;
            int ia = pair*2, ib = ia+1;
            int   Da = ch ? adR[ia] : adL[ia];
            int   Db = ch ? adR[ib] : adL[ib];
            float fa = ch ? afbR[ia] : afbL[ia];
            float fb = ch ? afbR[ib] : afbL[ib];
            float coef = 1.f; int lag = 0;
            if (ma > 0) { coef *= -powf(fa,(float)(ma-1)); lag += ma*Da; }
            if (mb > 0) { coef *= -powf(fb,(float)(mb-1)); lag += mb*Db; }
            if (fabsf(coef) > CUT) {
                unsigned slot = atomicAdd(&lcnt[lidx], 1u);
                if (slot < LISTCAP) {
                    lags [lidx*LISTCAP+slot] = lag;
                    coefs[lidx*LISTCAP+slot] = coef;
                }
            }
        }
    }

    // ---- phase 1: comb bank -> y  (16 threads/sample, 4-way ILP split) ----
    {
        const int NU = 16*T;
        for (int u = gtid; u < NU; u += NT) {
            int t = u >> 4, f = u & 15, c = f & 7, right = f >> 3;
            int   D  = right ? cdR[c] : cdL[c];
            float fb = right ? cfbR[c] : cfbL[c];
            float c0=1.f, c1=fb, c2=fb*fb, c3=c2*fb, r4=c2*c2;
            float a0=0.f, a1=0.f, a2=0.f, a3=0.f;
            int i0=t-D, i1=i0-D, i2=i1-D, i3=i2-D, s4=4*D;
            while (i3 >= 0) {
                a0=fmaf(c0,x[i0],a0); a1=fmaf(c1,x[i1],a1);
                a2=fmaf(c2,x[i2],a2); a3=fmaf(c3,x[i3],a3);
                c0*=r4; c1*=r4; c2*=r4; c3*=r4;
                i0-=s4; i1-=s4; i2-=s4; i3-=s4;
            }
            if (i0 >= 0) { a0=fmaf(c0,x[i0],a0);
                if (i1 >= 0) { a1=fmaf(c1,x[i1],a1);
                    if (i2 >= 0) a2=fmaf(c2,x[i2],a2); } }
            float acc = (a0+a1)+(a2+a3);
            acc += __shfl_xor(acc, 1);
            acc += __shfl_xor(acc, 2);
            acc += __shfl_xor(acc, 4);
            if (c == 0) y[right*(size_t)T + t] = acc;
        }
    }
    gridbar(cells, 0);

    // ---- phase 2: z = h01 (*) y  (coalesced: thread owns a sample) ----
    {
        const int NU = 4*T;      // u = t*4 + ch*2 + j ; j in {0,1} splits list
        for (int u = gtid; u < NU; u += NT) {
            int j = u & 1, ch = (u >> 1) & 1, t = u >> 2;
            int lidx = ch;                         // pair 0
            const float* in = y + ch*(size_t)T;
            unsigned cnt = lcnt[lidx];
            int count = (cnt < (unsigned)LISTCAP) ? (int)cnt : LISTCAP;
            float acc = 0.f;
            for (int k = j; k < count; k += 2) {
                int idx = t - lags[lidx*LISTCAP+k];
                if (idx >= 0) acc = fmaf(coefs[lidx*LISTCAP+k], in[idx], acc);
            }
            acc += __shfl_xor(acc, 1);             // j-pair reduce
            if (j == 0) z[ch*(size_t)T + t] = acc;
        }
    }
    gridbar(cells, 1);

    // ---- phase 3: w = h23 (*) z, mix, store ----
    {
        float wet = wetp[0], dry = dryp[0], width = widthp[0];
        float wet1 = wet*(width+1.f)*0.5f;
        float wet2 = wet*(1.f-width)*0.5f;
        const int NU = 4*T;
        for (int u = gtid; u < NU; u += NT) {
            int j = u & 1, ch = (u >> 1) & 1, t = u >> 2;
            int lidx = 2 + ch;                     // pair 1
            const float* in = z + ch*(size_t)T;
            unsigned cnt = lcnt[lidx];
            int count = (cnt < (unsigned)LISTCAP) ? (int)cnt : LISTCAP;
            float acc = 0.f;
            for (int k = j; k < count; k += 2) {
                int idx = t - lags[lidx*LISTCAP+k];
                if (idx >= 0) acc = fmaf(coefs[lidx*LISTCAP+k], in[idx], acc);
            }
            acc += __shfl_xor(acc, 1);             // j-pair reduce
            float other = __shfl_xor(acc, 2);      // channel exchange
            if (j == 0)
                out[2*(size_t)t + ch] = fmaf(acc, wet1, fmaf(other, wet2, x[t]*dry));
        }
    }
}

extern "C" void kernel_launch(void* const* d_in, const int* in_sizes, int n_in,
                              void* d_out, int out_size, void* d_ws, size_t ws_size,
                              hipStream_t stream) {
    const float* x            = (const float*)d_in[0];
    const float* comb_fb_L    = (const float*)d_in[1];
    const float* comb_fb_R    = (const float*)d_in[2];
    const float* ap_fb_L      = (const float*)d_in[3];
    const float* ap_fb_R      = (const float*)d_in[4];
    const float* wet          = (const float*)d_in[5];
    const float* dry          = (const float*)d_in[6];
    const float* width        = (const float*)d_in[7];
    const int*   comb_delay_L = (const int*)d_in[8];
    const int*   comb_delay_R = (const int*)d_in[9];
    const int*   ap_delay_L   = (const int*)d_in[10];
    const int*   ap_delay_R   = (const int*)d_in[11];
    const int T = in_sizes[0];

    // zero barrier cells + list counters (ws is poisoned 0xAA before every launch)
    hipMemsetAsync(d_ws, 0, 256, stream);

    freeverb_fused<<<NBLK, NTHR, 0, stream>>>(
        x, comb_fb_L, comb_fb_R, ap_fb_L, ap_fb_R,
        wet, dry, width, comb_delay_L, comb_delay_R, ap_delay_L, ap_delay_R,
        (float*)d_out, (unsigned char*)d_ws, T);
}

// Round 5
// 162.698 us; speedup vs baseline: 3.0951x; 2.9961x over previous
//
#include <hip/hip_runtime.h>

// Freeverb via closed-form IR expansion — 3 kernels, kernel-boundary sync.
//
// K1: comb bank  y[t] = sum_m fb^(m-1) x[t-mD]  (exact); block 0 also builds
//     the 4 allpass-pair term lists (visible to K2/K3 via kernel boundary).
// K2: z = h01 (*) y   (pair-IR sparse convolution, lists cached in LDS)
// K3: out = mix(h23 (*) z)
//
// Allpass H(z) = -1 + z^-D/(1-fb z^-D)  =>  h = -delta + g, g[m*D]=fb^(m-1)
// Pair IR: h01 = delta - g0 - g1 + g0(*)g1  (~276 terms at |c|>3e-7)
//
// Round-5 change vs round 4: NO grid barriers / fences. Round 3/4 showed the
// fused kernel stuck at ~410-437 us with VALUBusy 5% regardless of load
// coalescing -> agent-scope fence cost (per-wave L2 writeback walks across
// 8 XCDs) dominated. Kernel boundaries give cross-XCD visibility for free.
//
// ws layout (bytes):
//   32    : unsigned list_cnt[4]        idx = pair*2 + ch   (zeroed by K1 blk0)
//   256   : int   lags [4][LISTCAP]
//   8448  : float coefs[4][LISTCAP]
//   16896 : float y[2][T]  then  float z[2][T]

#define NTHR 512
#define LISTCAP 512
#define CUT 3e-7f

__global__ __launch_bounds__(NTHR) void k_comb(
    const float* __restrict__ x,
    const float* __restrict__ cfbL, const float* __restrict__ cfbR,
    const float* __restrict__ afbL, const float* __restrict__ afbR,
    const int* __restrict__ cdL, const int* __restrict__ cdR,
    const int* __restrict__ adL, const int* __restrict__ adR,
    unsigned char* __restrict__ ws, int T)
{
    unsigned* lcnt  = (unsigned*)(ws + 32);
    int*      lags  = (int*)(ws + 256);
    float*    coefs = (float*)(ws + 256 + 4*LISTCAP*4);
    float*    y     = (float*)(ws + 16896);

    // ---- block 0: zero counters, then build the 4 pair term lists ----
    if (blockIdx.x == 0) {
        if (threadIdx.x < 4) lcnt[threadIdx.x] = 0;
        __syncthreads();
        const int M = 25;   // singles m<=22, pairs ma+mb<=23 at CUT=3e-7 (fb=.5)
        for (int q = threadIdx.x; q < 4*M*M; q += NTHR) {
            int lidx = q / (M*M);
            int rem  = q - lidx*(M*M);
            int ma = rem / M, mb = rem % M;
            int pair = lidx >> 1, ch = lidx & 1;
            int ia = pair*2, ib = ia+1;
            int   Da = ch ? adR[ia] : adL[ia];
            int   Db = ch ? adR[ib] : adL[ib];
            float fa = ch ? afbR[ia] : afbL[ia];
            float fb = ch ? afbR[ib] : afbL[ib];
            float coef = 1.f; int lag = 0;
            if (ma > 0) { coef *= -powf(fa,(float)(ma-1)); lag += ma*Da; }
            if (mb > 0) { coef *= -powf(fb,(float)(mb-1)); lag += mb*Db; }
            if (fabsf(coef) > CUT) {
                unsigned slot = atomicAdd(&lcnt[lidx], 1u);
                if (slot < LISTCAP) {
                    lags [lidx*LISTCAP+slot] = lag;
                    coefs[lidx*LISTCAP+slot] = coef;
                }
            }
        }
    }

    // ---- comb bank -> y  (16 threads/sample, 4-way ILP split) ----
    const int NU = 16*T;
    const int NT = gridDim.x * NTHR;
    for (int u = blockIdx.x*NTHR + threadIdx.x; u < NU; u += NT) {
        int t = u >> 4, f = u & 15, c = f & 7, right = f >> 3;
        int   D  = right ? cdR[c] : cdL[c];
        float fb = right ? cfbR[c] : cfbL[c];
        float c0=1.f, c1=fb, c2=fb*fb, c3=c2*fb, r4=c2*c2;
        float a0=0.f, a1=0.f, a2=0.f, a3=0.f;
        int i0=t-D, i1=i0-D, i2=i1-D, i3=i2-D, s4=4*D;
        while (i3 >= 0) {
            a0=fmaf(c0,x[i0],a0); a1=fmaf(c1,x[i1],a1);
            a2=fmaf(c2,x[i2],a2); a3=fmaf(c3,x[i3],a3);
            c0*=r4; c1*=r4; c2*=r4; c3*=r4;
            i0-=s4; i1-=s4; i2-=s4; i3-=s4;
        }
        if (i0 >= 0) { a0=fmaf(c0,x[i0],a0);
            if (i1 >= 0) { a1=fmaf(c1,x[i1],a1);
                if (i2 >= 0) a2=fmaf(c2,x[i2],a2); } }
        float acc = (a0+a1)+(a2+a3);
        acc += __shfl_xor(acc, 1);
        acc += __shfl_xor(acc, 2);
        acc += __shfl_xor(acc, 4);
        if (c == 0) y[right*(size_t)T + t] = acc;
    }
}

// Sparse pair-IR convolution. pair=0: in=y -> zout. pair=1 (final): in=z,
// mixes both channels into interleaved out.
__global__ __launch_bounds__(NTHR) void k_conv(
    const float* __restrict__ inbase, int pair, int is_final,
    float* __restrict__ zout,
    const float* __restrict__ x,
    const float* __restrict__ wetp, const float* __restrict__ dryp,
    const float* __restrict__ widthp,
    float* __restrict__ out,
    const unsigned char* __restrict__ ws, int T)
{
    const unsigned* lcnt  = (const unsigned*)(ws + 32);
    const int*      lags  = (const int*)(ws + 256);
    const float*    coefs = (const float*)(ws + 256 + 4*LISTCAP*4);

    __shared__ int   s_lag [2*LISTCAP];
    __shared__ float s_coef[2*LISTCAP];
    {
        int base = (pair*2)*LISTCAP;
        for (int i = threadIdx.x; i < 2*LISTCAP; i += NTHR) {
            s_lag [i] = lags [base + i];
            s_coef[i] = coefs[base + i];
        }
    }
    __syncthreads();

    int u = blockIdx.x*NTHR + threadIdx.x;     // u = t*4 + ch*2 + j
    if (u >= 4*T) return;
    int j = u & 1, ch = (u >> 1) & 1, t = u >> 2;
    const float* __restrict__ in = inbase + ch*(size_t)T;
    unsigned cnt = lcnt[pair*2 + ch];
    int count = (cnt < (unsigned)LISTCAP) ? (int)cnt : LISTCAP;

    float acc = 0.f;
    for (int k = j; k < count; k += 2) {
        int idx = t - s_lag[ch*LISTCAP + k];
        if (idx >= 0) acc = fmaf(s_coef[ch*LISTCAP + k], in[idx], acc);
    }
    acc += __shfl_xor(acc, 1);                 // j-pair reduce

    if (!is_final) {
        if (j == 0) zout[ch*(size_t)T + t] = acc;
    } else {
        float other = __shfl_xor(acc, 2);      // channel exchange
        float wet = wetp[0], dry = dryp[0], width = widthp[0];
        float wet1 = wet*(width+1.f)*0.5f;
        float wet2 = wet*(1.f-width)*0.5f;
        if (j == 0)
            out[2*(size_t)t + ch] = fmaf(acc, wet1, fmaf(other, wet2, x[t]*dry));
    }
}

extern "C" void kernel_launch(void* const* d_in, const int* in_sizes, int n_in,
                              void* d_out, int out_size, void* d_ws, size_t ws_size,
                              hipStream_t stream) {
    const float* x            = (const float*)d_in[0];
    const float* comb_fb_L    = (const float*)d_in[1];
    const float* comb_fb_R    = (const float*)d_in[2];
    const float* ap_fb_L      = (const float*)d_in[3];
    const float* ap_fb_R      = (const float*)d_in[4];
    const float* wet          = (const float*)d_in[5];
    const float* dry          = (const float*)d_in[6];
    const float* width        = (const float*)d_in[7];
    const int*   comb_delay_L = (const int*)d_in[8];
    const int*   comb_delay_R = (const int*)d_in[9];
    const int*   ap_delay_L   = (const int*)d_in[10];
    const int*   ap_delay_R   = (const int*)d_in[11];
    const int T = in_sizes[0];

    unsigned char* ws = (unsigned char*)d_ws;
    float* y   = (float*)(ws + 16896);
    float* z   = y + 2*(size_t)T;
    float* out = (float*)d_out;

    int cb = (16*T + NTHR-1) / NTHR;   // 2048 blocks at T=65536
    int vb = (4*T  + NTHR-1) / NTHR;   // 512 blocks

    k_comb<<<cb, NTHR, 0, stream>>>(x, comb_fb_L, comb_fb_R, ap_fb_L, ap_fb_R,
                                    comb_delay_L, comb_delay_R,
                                    ap_delay_L, ap_delay_R, ws, T);

    k_conv<<<vb, NTHR, 0, stream>>>(y, 0, 0, z, x, wet, dry, width, out, ws, T);
    k_conv<<<vb, NTHR, 0, stream>>>(z, 1, 1, nullptr, x, wet, dry, width, out, ws, T);
}

// Round 6
// 125.639 us; speedup vs baseline: 4.0081x; 1.2950x over previous
//
#include <hip/hip_runtime.h>

// Freeverb via closed-form IR expansion — 3 kernels, kernel-boundary sync.
//
// K1: comb bank  y[t] = sum_m fb^(m-1) x[t-mD]  (exact); block 0 also builds
//     the 4 allpass-pair term lists (visible to K2/K3 via kernel boundary).
// K2: z = h01 (*) y   (pair-IR sparse convolution)
// K3: out = mix(h23 (*) z)
//
// Allpass H(z) = -1 + z^-D/(1-fb z^-D)  =>  h = -delta + g, g[m*D]=fb^(m-1)
// Pair IR: h01 = delta - g0 - g1 + g0(*)g1  (~298 terms at |c|>3e-7)
//
// Round-6 change (perf only): 4 samples per thread everywhere. Per term:
// one unaligned 16B load (global_load_dwordx4) + 4 FMAs + one ds_read_b64
// for the packed (lag,coef) pair — ~3-4x fewer issued instructions per
// sample than round 5 (which was ~8 instr/sample and ~30+ us per conv).
//
// ws layout (bytes):
//   32    : unsigned lcnt[4]            idx = pair*2 + ch   (zeroed by K1 blk0)
//   256   : int2 terms[4][LISTCAP]      (lag, coef-as-int)  16 KB
//   16896 : float y[2][T]  then  float z[2][T]

#define NTHR 512
#define LISTCAP 512
#define CUT 3e-7f

__global__ __launch_bounds__(NTHR) void k_comb(
    const float* __restrict__ x,
    const float* __restrict__ cfbL, const float* __restrict__ cfbR,
    const float* __restrict__ afbL, const float* __restrict__ afbR,
    const int* __restrict__ cdL, const int* __restrict__ cdR,
    const int* __restrict__ adL, const int* __restrict__ adR,
    unsigned char* __restrict__ ws, int T)
{
    unsigned* lcnt  = (unsigned*)(ws + 32);
    int2*     terms = (int2*)(ws + 256);
    float*    y     = (float*)(ws + 16896);

    // ---- block 0: zero counters, build the 4 pair term lists ----
    if (blockIdx.x == 0) {
        if (threadIdx.x < 4) lcnt[threadIdx.x] = 0;
        __syncthreads();
        const int M = 25;   // singles m<=22, pairs ma+mb<=23 at CUT=3e-7 (fb=.5)
        for (int q = threadIdx.x; q < 4*M*M; q += NTHR) {
            int lidx = q / (M*M);
            int rem  = q - lidx*(M*M);
            int ma = rem / M, mb = rem % M;
            int pair = lidx >> 1, ch = lidx & 1;
            int ia = pair*2, ib = ia+1;
            int   Da = ch ? adR[ia] : adL[ia];
            int   Db = ch ? adR[ib] : adL[ib];
            float fa = ch ? afbR[ia] : afbL[ia];
            float fb = ch ? afbR[ib] : afbL[ib];
            float coef = 1.f; int lag = 0;
            if (ma > 0) { coef *= -powf(fa,(float)(ma-1)); lag += ma*Da; }
            if (mb > 0) { coef *= -powf(fb,(float)(mb-1)); lag += mb*Db; }
            if (fabsf(coef) > CUT) {
                unsigned slot = atomicAdd(&lcnt[lidx], 1u);
                if (slot < LISTCAP)
                    terms[lidx*LISTCAP + slot] = make_int2(lag, __float_as_int(coef));
            }
        }
    }

    // ---- comb bank -> y : thread = (comb c, channel ch, 4-sample group t4)
    // lane bits [0:2]=c, [3]=ch, [4:5]=low t4 bits -> per (c,ch) 4 lanes read
    // 16B-contiguous; reduce over c via shfl_xor 1,2,4.
    const int NT4 = T >> 2;
    int tid = blockIdx.x*NTHR + threadIdx.x;
    int c = tid & 7, ch = (tid >> 3) & 1, t4 = tid >> 4;
    float a0=0.f, a1=0.f, a2=0.f, a3=0.f;
    if (t4 < NT4) {
        int   D  = ch ? cdR[c] : cdL[c];
        float fb = ch ? cfbR[c] : cfbL[c];
        float coef = 1.f;
        int idx = 4*t4 - D;
        while (idx >= 0) {
            float4 v; __builtin_memcpy(&v, x + idx, 16);
            a0 = fmaf(coef, v.x, a0); a1 = fmaf(coef, v.y, a1);
            a2 = fmaf(coef, v.z, a2); a3 = fmaf(coef, v.w, a3);
            coef *= fb; idx -= D;
        }
        if (idx >= -3) {            // partial group at the t=lag boundary
            if (idx == -1)      { a1=fmaf(coef,x[0],a1); a2=fmaf(coef,x[1],a2); a3=fmaf(coef,x[2],a3); }
            else if (idx == -2) { a2=fmaf(coef,x[0],a2); a3=fmaf(coef,x[1],a3); }
            else                { a3=fmaf(coef,x[0],a3); }
        }
    }
    a0 += __shfl_xor(a0,1); a0 += __shfl_xor(a0,2); a0 += __shfl_xor(a0,4);
    a1 += __shfl_xor(a1,1); a1 += __shfl_xor(a1,2); a1 += __shfl_xor(a1,4);
    a2 += __shfl_xor(a2,1); a2 += __shfl_xor(a2,2); a2 += __shfl_xor(a2,4);
    a3 += __shfl_xor(a3,1); a3 += __shfl_xor(a3,2); a3 += __shfl_xor(a3,4);
    if (c == 0 && t4 < NT4) {
        float4 o; o.x=a0; o.y=a1; o.z=a2; o.w=a3;
        *(float4*)(y + ch*(size_t)T + 4*t4) = o;   // 16B-aligned
    }
}

// K2: z = h01 (*) y.  thread = (j of 8-way list split, 4-sample group).
// ch comes from blockIdx.y. lane bits [0:2]=s (consecutive t4), [3:5]=j.
__global__ __launch_bounds__(NTHR) void k_conv01(
    const unsigned char* __restrict__ ws, int T)
{
    const unsigned* lcnt  = (const unsigned*)(ws + 32);
    const int2*     terms = (const int2*)(ws + 256);
    const float*    y     = (const float*)(ws + 16896);
    float*          z     = (float*)(ws + 16896) + 2*(size_t)T;

    __shared__ int2 s_t[LISTCAP];
    const int ch = blockIdx.y;                  // pair 0 -> lidx = ch
    for (int i = threadIdx.x; i < LISTCAP; i += NTHR)
        s_t[i] = terms[ch*LISTCAP + i];
    __syncthreads();
    int count = (int)lcnt[ch]; if (count > LISTCAP) count = LISTCAP;

    const int NT4 = T >> 2;
    int tid = blockIdx.x*NTHR + threadIdx.x;
    int s = tid & 7, j = (tid >> 3) & 7, w = tid >> 6;
    int t4 = w*8 + s;
    const float* __restrict__ in = y + ch*(size_t)T;
    float a0=0.f, a1=0.f, a2=0.f, a3=0.f;
    if (t4 < NT4) {
        int t0 = 4*t4;
        for (int k = j; k < count; k += 8) {
            int2 p = s_t[k];                    // one ds_read_b64
            float cf = __int_as_float(p.y);
            int base = t0 - p.x;
            if (base >= 0) {
                float4 v; __builtin_memcpy(&v, in + base, 16);
                a0=fmaf(cf,v.x,a0); a1=fmaf(cf,v.y,a1);
                a2=fmaf(cf,v.z,a2); a3=fmaf(cf,v.w,a3);
            } else if (base >= -3) {
                if (base == -1)      { a1=fmaf(cf,in[0],a1); a2=fmaf(cf,in[1],a2); a3=fmaf(cf,in[2],a3); }
                else if (base == -2) { a2=fmaf(cf,in[0],a2); a3=fmaf(cf,in[1],a3); }
                else                 { a3=fmaf(cf,in[0],a3); }
            }
        }
    }
    a0 += __shfl_xor(a0,8); a0 += __shfl_xor(a0,16); a0 += __shfl_xor(a0,32);
    a1 += __shfl_xor(a1,8); a1 += __shfl_xor(a1,16); a1 += __shfl_xor(a1,32);
    a2 += __shfl_xor(a2,8); a2 += __shfl_xor(a2,16); a2 += __shfl_xor(a2,32);
    a3 += __shfl_xor(a3,8); a3 += __shfl_xor(a3,16); a3 += __shfl_xor(a3,32);
    if (j == 0 && t4 < NT4) {
        float4 o; o.x=a0; o.y=a1; o.z=a2; o.w=a3;
        *(float4*)(z + ch*(size_t)T + 4*t4) = o;   // 16B-aligned
    }
}

// K3: out = mix(h23 (*) z). lane bits [0:2]=s, [3:4]=j (4-way), [5]=ch.
// Channel exchange via shfl_xor 32; interleaved stereo stored as 2x float4.
__global__ __launch_bounds__(NTHR) void k_conv23(
    const float* __restrict__ x,
    const float* __restrict__ wetp, const float* __restrict__ dryp,
    const float* __restrict__ widthp,
    float* __restrict__ out,
    const unsigned char* __restrict__ ws, int T)
{
    const unsigned* lcnt  = (const unsigned*)(ws + 32);
    const int2*     terms = (const int2*)(ws + 256);
    const float*    zb    = (const float*)(ws + 16896) + 2*(size_t)T;

    __shared__ int2 s_t[2*LISTCAP];             // [ch][k], pair 1 -> lidx = 2+ch
    for (int i = threadIdx.x; i < 2*LISTCAP; i += NTHR)
        s_t[i] = terms[2*LISTCAP + i];
    __syncthreads();

    const int NT4 = T >> 2;
    int tid = blockIdx.x*NTHR + threadIdx.x;
    int s = tid & 7, j = (tid >> 3) & 3, ch = (tid >> 5) & 1, w = tid >> 6;
    int t4 = w*8 + s;
    int count = (int)lcnt[2 + ch]; if (count > LISTCAP) count = LISTCAP;
    const float* __restrict__ in = zb + ch*(size_t)T;
    float a0=0.f, a1=0.f, a2=0.f, a3=0.f;
    if (t4 < NT4) {
        int t0 = 4*t4;
        const int2* lst = s_t + ch*LISTCAP;
        for (int k = j; k < count; k += 4) {
            int2 p = lst[k];
            float cf = __int_as_float(p.y);
            int base = t0 - p.x;
            if (base >= 0) {
                float4 v; __builtin_memcpy(&v, in + base, 16);
                a0=fmaf(cf,v.x,a0); a1=fmaf(cf,v.y,a1);
                a2=fmaf(cf,v.z,a2); a3=fmaf(cf,v.w,a3);
            } else if (base >= -3) {
                if (base == -1)      { a1=fmaf(cf,in[0],a1); a2=fmaf(cf,in[1],a2); a3=fmaf(cf,in[2],a3); }
                else if (base == -2) { a2=fmaf(cf,in[0],a2); a3=fmaf(cf,in[1],a3); }
                else                 { a3=fmaf(cf,in[0],a3); }
            }
        }
    }
    a0 += __shfl_xor(a0,8); a0 += __shfl_xor(a0,16);
    a1 += __shfl_xor(a1,8); a1 += __shfl_xor(a1,16);
    a2 += __shfl_xor(a2,8); a2 += __shfl_xor(a2,16);
    a3 += __shfl_xor(a3,8); a3 += __shfl_xor(a3,16);
    float o0 = __shfl_xor(a0,32), o1 = __shfl_xor(a1,32);
    float o2 = __shfl_xor(a2,32), o3 = __shfl_xor(a3,32);
    if (j == 0 && ch == 0 && t4 < NT4) {
        float wet = wetp[0], dry = dryp[0], width = widthp[0];
        float wet1 = wet*(width+1.f)*0.5f;
        float wet2 = wet*(1.f-width)*0.5f;
        float4 xv = *(const float4*)(x + 4*t4);   // 16B-aligned
        float oL0 = fmaf(a0,wet1, fmaf(o0,wet2, xv.x*dry));
        float oR0 = fmaf(o0,wet1, fmaf(a0,wet2, xv.x*dry));
        float oL1 = fmaf(a1,wet1, fmaf(o1,wet2, xv.y*dry));
        float oR1 = fmaf(o1,wet1, fmaf(a1,wet2, xv.y*dry));
        float oL2 = fmaf(a2,wet1, fmaf(o2,wet2, xv.z*dry));
        float oR2 = fmaf(o2,wet1, fmaf(a2,wet2, xv.z*dry));
        float oL3 = fmaf(a3,wet1, fmaf(o3,wet2, xv.w*dry));
        float oR3 = fmaf(o3,wet1, fmaf(a3,wet2, xv.w*dry));
        float4 r0; r0.x=oL0; r0.y=oR0; r0.z=oL1; r0.w=oR1;
        float4 r1; r1.x=oL2; r1.y=oR2; r1.z=oL3; r1.w=oR3;
        ((float4*)out)[2*(size_t)t4]     = r0;     // out[8t4 .. 8t4+3]
        ((float4*)out)[2*(size_t)t4 + 1] = r1;     // out[8t4+4 .. 8t4+7]
    }
}

extern "C" void kernel_launch(void* const* d_in, const int* in_sizes, int n_in,
                              void* d_out, int out_size, void* d_ws, size_t ws_size,
                              hipStream_t stream) {
    const float* x            = (const float*)d_in[0];
    const float* comb_fb_L    = (const float*)d_in[1];
    const float* comb_fb_R    = (const float*)d_in[2];
    const float* ap_fb_L      = (const float*)d_in[3];
    const float* ap_fb_R      = (const float*)d_in[4];
    const float* wet          = (const float*)d_in[5];
    const float* dry          = (const float*)d_in[6];
    const float* width        = (const float*)d_in[7];
    const int*   comb_delay_L = (const int*)d_in[8];
    const int*   comb_delay_R = (const int*)d_in[9];
    const int*   ap_delay_L   = (const int*)d_in[10];
    const int*   ap_delay_R   = (const int*)d_in[11];
    const int T = in_sizes[0];

    unsigned char* ws = (unsigned char*)d_ws;
    const int NT4 = T >> 2;

    int b1 = (16*NT4 + NTHR-1) / NTHR;   // 512 blocks at T=65536
    int b2 = (8*NT4  + NTHR-1) / NTHR;   // 256
    int b3 = (8*NT4  + NTHR-1) / NTHR;   // 256

    k_comb<<<b1, NTHR, 0, stream>>>(x, comb_fb_L, comb_fb_R, ap_fb_L, ap_fb_R,
                                    comb_delay_L, comb_delay_R,
                                    ap_delay_L, ap_delay_R, ws, T);

    k_conv01<<<dim3(b2, 2), NTHR, 0, stream>>>(ws, T);

    k_conv23<<<b3, NTHR, 0, stream>>>(x, wet, dry, width, (float*)d_out, ws, T);
}